// Round 3
// baseline (208.671 us; speedup 1.0000x reference)
//
#include <hip/hip_runtime.h>

typedef __attribute__((ext_vector_type(8))) short short8;
typedef __attribute__((ext_vector_type(4))) short short4v;
typedef __attribute__((ext_vector_type(4))) float float4v;

#define MFMA16(a, b, c) __builtin_amdgcn_mfma_f32_16x16x32_bf16((a), (b), (c), 0, 0, 0)

constexpr int kN = 512;
constexpr int kD = 64;
constexpr int kThreads = 1024;  // 16 waves -> 4 waves/SIMD (needs VGPR<=128)

// LDS layout (ushort elements):
//   [0,      32768)  K swizzled bf16 (B-operand for QK^T, channel-contiguous):
//                      elem (n,d) at (d>>3)*4096 + n*8 + (d&7)
//   [32768,  65536)  V swizzled bf16 (B-operand for PV, POSITION-contiguous):
//                      elem (n,d) at (n>>3)*512 + d*8 + (n&7)
//   [65536,  69632)  Wdsw: Wv staging during phase 1; Wd (B-swizzle) in phase 2/3
//   [69632,  79872)  rep: Wq (0..4096) + Wk (4096..8192) staging during phase 1;
//                    reused as 16 per-wave repack buffers (16 rows x 40, padded)
constexpr int LDS_TOTAL_BYTES = 79872 * 2;  // 156 KiB

static __device__ __forceinline__ unsigned short f2bf(float f) {
  unsigned int u = __float_as_uint(f);
  u = (u + 0x7fffu + ((u >> 16) & 1u)) >> 16;
  return (unsigned short)u;
}

__global__ __launch_bounds__(kThreads, 4) void ts_attn_fused(
    const float* __restrict__ x, const float* __restrict__ Wq_t,
    const float* __restrict__ Wk_t, const float* __restrict__ Wv_t,
    const float* __restrict__ Wq_s, const float* __restrict__ Wk_s,
    const float* __restrict__ Wv_s, const float* __restrict__ Wd_t,
    const float* __restrict__ bd_t, const float* __restrict__ Wd_s,
    const float* __restrict__ bd_s, float* __restrict__ out,
    unsigned short* __restrict__ qws) {
  extern __shared__ __align__(16) unsigned short smem_us[];
  unsigned short* Ksw = smem_us;           // 32768 elems
  unsigned short* Vsw = smem_us + 32768;   // 32768 elems
  unsigned short* Wdsw = smem_us + 65536;  // 4096 elems
  unsigned short* rep = smem_us + 69632;   // 10240 elems

  const int tid = threadIdx.x;
  const int wv = tid >> 6;   // wave 0..15
  const int lane = tid & 63;
  const int ln = lane & 15;
  const int quad = lane >> 4;
  const int b = blockIdx.x;

  const float* xb = x + (size_t)b * (kN * kD);
  float* outb = out + (size_t)b * (kN * kD);
  unsigned short* qb = qws + (size_t)b * (kN * kD);  // per-batch Q (bf16, A-swizzle)

  // staging indices: each thread covers (d, e0..e0+3)
  const int sd = tid >> 4;          // 0..63
  const int se0 = (tid & 15) * 4;   // 0..60
  const int sbase = (sd >> 3) * 512 + (sd & 7);

  float bdsum[4];
#pragma unroll
  for (int nt = 0; nt < 4; ++nt) bdsum[nt] = bd_t[nt * 16 + ln] + bd_s[nt * 16 + ln];

  float4v acc_t[2][4];  // temporal-branch dense output, kept in registers

#pragma unroll 1
  for (int br = 0; br < 2; ++br) {
    const float* Wq = br ? Wq_s : Wq_t;
    const float* Wk = br ? Wk_s : Wk_t;
    const float* Wv = br ? Wv_s : Wv_t;
    const float* Wd = br ? Wd_s : Wd_t;

    // ---- stage Wq, Wk, Wv into LDS (bf16, B-operand swizzle) ----
    {
      const float* srcs[3] = {Wq, Wk, Wv};
      unsigned short* dsts[3] = {rep, rep + 4096, Wdsw};
#pragma unroll
      for (int g = 0; g < 3; ++g) {
        const float4v u = *reinterpret_cast<const float4v*>(srcs[g] + sd * 64 + se0);
        unsigned short* dst = dsts[g];
#pragma unroll
        for (int i = 0; i < 4; ++i) dst[sbase + (se0 + i) * 8] = f2bf(u[i]);
      }
    }
    __syncthreads();

    // ---- phase 1: Q,K,V = X @ W (MFMA). K,V -> LDS; Q -> global ws ----
#pragma unroll 1
    for (int mi = 0; mi < 2; ++mi) {
      const int mt = wv + mi * 16;  // m-tile 0..31
      const int mrow = mt * 16 + ln;
      short8 xa0, xa1;
      {
        const float4v* p0 = reinterpret_cast<const float4v*>(xb + mrow * 64 + quad * 8);
        const float4v u0 = p0[0], v0 = p0[1];
        const float4v* p1 = reinterpret_cast<const float4v*>(xb + mrow * 64 + 32 + quad * 8);
        const float4v u1 = p1[0], v1 = p1[1];
#pragma unroll
        for (int i = 0; i < 4; ++i) {
          xa0[i] = (short)f2bf(u0[i]);
          xa0[4 + i] = (short)f2bf(v0[i]);
          xa1[i] = (short)f2bf(u1[i]);
          xa1[4 + i] = (short)f2bf(v1[i]);
        }
      }
#pragma unroll
      for (int g = 0; g < 3; ++g) {
        const unsigned short* Wl = (g == 0) ? rep : (g == 1) ? (rep + 4096) : Wdsw;
#pragma unroll
        for (int nt = 0; nt < 4; ++nt) {
          const short8 b0 = *reinterpret_cast<const short8*>(Wl + quad * 512 + (nt * 16 + ln) * 8);
          const short8 b1 = *reinterpret_cast<const short8*>(Wl + (4 + quad) * 512 + (nt * 16 + ln) * 8);
          float4v acc = {0.f, 0.f, 0.f, 0.f};
          acc = MFMA16(xa0, b0, acc);
          acc = MFMA16(xa1, b1, acc);
          // D-frag: element (row = mt*16 + quad*4 + r, col e = nt*16 + ln)
          if (g == 0) {
            const int ehi = nt * 2 + (ln >> 3);
            const int elo = ln & 7;
#pragma unroll
            for (int r = 0; r < 4; ++r)
              qb[ehi * 4096 + (mt * 16 + quad * 4 + r) * 8 + elo] = f2bf(acc[r]);
          } else if (g == 1) {
            const int ehi = nt * 2 + (ln >> 3);
            const int elo = ln & 7;
#pragma unroll
            for (int r = 0; r < 4; ++r)
              Ksw[ehi * 4096 + (mt * 16 + quad * 4 + r) * 8 + elo] = f2bf(acc[r]);
          } else {
            short4v pk;
#pragma unroll
            for (int r = 0; r < 4; ++r) pk[r] = (short)f2bf(acc[r]);
            const int vbase =
                (mt * 2 + (quad >> 1)) * 512 + (nt * 16 + ln) * 8 + (quad & 1) * 4;
            *reinterpret_cast<short4v*>(Vsw + vbase) = pk;
          }
        }
      }
    }
    __syncthreads();

    // ---- stage Wd (overwrites Wv staging; V is already built) ----
    {
      const float4v u = *reinterpret_cast<const float4v*>(Wd + sd * 64 + se0);
#pragma unroll
      for (int i = 0; i < 4; ++i) Wdsw[sbase + (se0 + i) * 8] = f2bf(u[i]);
    }
    __syncthreads();

    // ---- phase 2/3: scores -> exp (no-max softmax) -> PV -> dense ----
    unsigned short* buf = rep + wv * 640;  // 16 x 40 repack buffer
#pragma unroll 1
    for (int qi = 0; qi < 2; ++qi) {
      const int qt = wv + qi * 16;
      const short8 q0 = *reinterpret_cast<const short8*>(qb + quad * 4096 + (qt * 16 + ln) * 8);
      const short8 q1 = *reinterpret_cast<const short8*>(qb + (4 + quad) * 4096 + (qt * 16 + ln) * 8);

      float sum[4] = {0.f, 0.f, 0.f, 0.f};
      float4v o[4];
#pragma unroll
      for (int i = 0; i < 4; ++i) o[i] = (float4v){0.f, 0.f, 0.f, 0.f};

#pragma unroll 2
      for (int kc = 0; kc < 16; ++kc) {
#pragma unroll
        for (int t2 = 0; t2 < 2; ++t2) {
          const int nt = kc * 2 + t2;
          const short8 k0 = *reinterpret_cast<const short8*>(Ksw + quad * 4096 + (nt * 16 + ln) * 8);
          const short8 k1 =
              *reinterpret_cast<const short8*>(Ksw + (4 + quad) * 4096 + (nt * 16 + ln) * 8);
          float4v acc = {0.f, 0.f, 0.f, 0.f};
          acc = MFMA16(q0, k0, acc);
          acc = MFMA16(q1, k1, acc);
#pragma unroll
          for (int r = 0; r < 4; ++r) {
            const float p = __expf(acc[r] * 0.125f);  // no max-shift: |s|<~10, fp32-safe
            sum[r] += p;
            buf[(quad * 4 + r) * 40 + t2 * 16 + ln] = f2bf(p);
          }
        }
        asm volatile("s_waitcnt lgkmcnt(0)" ::: "memory");
        const short8 pa = *reinterpret_cast<const short8*>(buf + ln * 40 + quad * 8);
#pragma unroll
        for (int nto = 0; nto < 4; ++nto) {
          const short8 vf =
              *reinterpret_cast<const short8*>(Vsw + (kc * 4 + quad) * 512 + (nto * 16 + ln) * 8);
          o[nto] = MFMA16(pa, vf, o[nto]);
        }
        asm volatile("s_waitcnt lgkmcnt(0)" ::: "memory");  // pa consumed before next pack
      }

      // row sums (within 16-lane group) -> 1/sum
#pragma unroll
      for (int dd = 1; dd < 16; dd <<= 1)
#pragma unroll
        for (int r = 0; r < 4; ++r) sum[r] += __shfl_xor(sum[r], dd, 64);
      float inv[4];
#pragma unroll
      for (int r = 0; r < 4; ++r) inv[r] = 1.0f / sum[r];

      // O (16x64) -> A-layout via buf, two 32-col passes
#pragma unroll
      for (int nto = 0; nto < 2; ++nto)
#pragma unroll
        for (int r = 0; r < 4; ++r)
          buf[(quad * 4 + r) * 40 + nto * 16 + ln] = f2bf(o[nto][r] * inv[r]);
      asm volatile("s_waitcnt lgkmcnt(0)" ::: "memory");
      const short8 a0 = *reinterpret_cast<const short8*>(buf + ln * 40 + quad * 8);
      asm volatile("s_waitcnt lgkmcnt(0)" ::: "memory");  // a0 landed before overwrite
#pragma unroll
      for (int nto = 2; nto < 4; ++nto)
#pragma unroll
        for (int r = 0; r < 4; ++r)
          buf[(quad * 4 + r) * 40 + (nto - 2) * 16 + ln] = f2bf(o[nto][r] * inv[r]);
      asm volatile("s_waitcnt lgkmcnt(0)" ::: "memory");
      const short8 a1 = *reinterpret_cast<const short8*>(buf + ln * 40 + quad * 8);

      // dense: O @ Wd; branch 0 kept in regs, branch 1 fused epilogue
#pragma unroll
      for (int nt = 0; nt < 4; ++nt) {
        const short8 w0 = *reinterpret_cast<const short8*>(Wdsw + quad * 512 + (nt * 16 + ln) * 8);
        const short8 w1 = *reinterpret_cast<const short8*>(Wdsw + (4 + quad) * 512 + (nt * 16 + ln) * 8);
        float4v d4 = {0.f, 0.f, 0.f, 0.f};
        d4 = MFMA16(a0, w0, d4);
        d4 = MFMA16(a1, w1, d4);
        if (br == 0) {
          acc_t[qi][nt] = d4;
        } else {
          const int m0 = qt * 16 + quad * 4;
          const int col = nt * 16 + ln;
#pragma unroll
          for (int r = 0; r < 4; ++r) {
            const float z = acc_t[qi][nt][r] + d4[r] + bdsum[nt];
            const float gate = 1.0f / (1.0f + __expf(-z));
            outb[(m0 + r) * 64 + col] = xb[(m0 + r) * 64 + col] * gate;
          }
        }
      }
    }
    __syncthreads();  // protect LDS/qb before next branch restages
  }
}

extern "C" void kernel_launch(void* const* d_in, const int* in_sizes, int n_in,
                              void* d_out, int out_size, void* d_ws, size_t ws_size,
                              hipStream_t stream) {
  const float* x = (const float*)d_in[0];
  const float* Wq_t = (const float*)d_in[1];
  const float* Wk_t = (const float*)d_in[2];
  const float* Wv_t = (const float*)d_in[3];
  const float* Wq_s = (const float*)d_in[4];
  const float* Wk_s = (const float*)d_in[5];
  const float* Wv_s = (const float*)d_in[6];
  const float* Wd_t = (const float*)d_in[7];
  const float* bd_t = (const float*)d_in[8];
  const float* Wd_s = (const float*)d_in[9];
  const float* bd_s = (const float*)d_in[10];
  float* out = (float*)d_out;
  unsigned short* qws = (unsigned short*)d_ws;  // needs 256*512*64*2 = 16 MiB

  hipFuncSetAttribute(reinterpret_cast<const void*>(ts_attn_fused),
                      hipFuncAttributeMaxDynamicSharedMemorySize, LDS_TOTAL_BYTES);
  ts_attn_fused<<<dim3(256), dim3(kThreads), LDS_TOTAL_BYTES, stream>>>(
      x, Wq_t, Wk_t, Wv_t, Wq_s, Wk_s, Wv_s, Wd_t, bd_t, Wd_s, bd_s, out, qws);
}

// Round 4
// 205.579 us; speedup vs baseline: 1.0150x; 1.0150x over previous
//
#include <hip/hip_runtime.h>

typedef __attribute__((ext_vector_type(8))) short short8;
typedef __attribute__((ext_vector_type(4))) short short4v;
typedef __attribute__((ext_vector_type(4))) float float4v;

#define MFMA16(a, b, c) __builtin_amdgcn_mfma_f32_16x16x32_bf16((a), (b), (c), 0, 0, 0)

constexpr int kN = 512;
constexpr int kD = 64;
constexpr int kThreads = 1024;  // 16 waves -> 4 waves/SIMD (hard req: VGPR<=128)

// LDS layout (ushort elements):
//   [0,      32768)  K swizzled bf16 (B-operand for QK^T, channel-contiguous):
//                      elem (n,d) at (d>>3)*4096 + n*8 + (d&7)
//   [32768,  65536)  V swizzled bf16 (B-operand for PV, POSITION-contiguous):
//                      elem (n,d) at (n>>3)*512 + d*8 + (n&7)
//   [65536,  69632)  Wdsw: Wv staging during phase 1; Wd (B-swizzle) in phase 2/3
//   [69632,  79872)  rep: Wq (0..4096) + Wk (4096..8192) staging during phase 1;
//                    reused as 16 per-wave repack buffers (16 rows x 40, padded)
constexpr int LDS_TOTAL_BYTES = 79872 * 2;  // 156 KiB -> 1 block/CU

static __device__ __forceinline__ unsigned short f2bf(float f) {
  unsigned int u = __float_as_uint(f);
  u = (u + 0x7fffu + ((u >> 16) & 1u)) >> 16;
  return (unsigned short)u;
}

__global__ __launch_bounds__(kThreads, 4) void ts_attn_fused(
    const float* __restrict__ x, const float* __restrict__ Wq_t,
    const float* __restrict__ Wk_t, const float* __restrict__ Wv_t,
    const float* __restrict__ Wq_s, const float* __restrict__ Wk_s,
    const float* __restrict__ Wv_s, const float* __restrict__ Wd_t,
    const float* __restrict__ bd_t, const float* __restrict__ Wd_s,
    const float* __restrict__ bd_s, float* __restrict__ out) {
  extern __shared__ __align__(16) unsigned short smem_us[];
  unsigned short* Ksw = smem_us;           // 32768 elems
  unsigned short* Vsw = smem_us + 32768;   // 32768 elems
  unsigned short* Wdsw = smem_us + 65536;  // 4096 elems
  unsigned short* rep = smem_us + 69632;   // 10240 elems

  const int tid = threadIdx.x;
  const int wv = tid >> 6;   // wave 0..15
  const int lane = tid & 63;
  const int ln = lane & 15;
  const int quad = lane >> 4;
  const int b = blockIdx.x;

  const float* xb = x + (size_t)b * (kN * kD);
  float* outb = out + (size_t)b * (kN * kD);

  // weight staging indices: thread covers (d, e0..e0+3)
  const int sd = tid >> 4;         // 0..63
  const int se0 = (tid & 15) * 4;  // 0..60
  const int sbase = (sd >> 3) * 512 + (sd & 7);

  float bdsum[4];
#pragma unroll
  for (int nt = 0; nt < 4; ++nt) bdsum[nt] = bd_t[nt * 16 + ln] + bd_s[nt * 16 + ln];

#pragma unroll 1
  for (int br = 0; br < 2; ++br) {
    const float* Wq = br ? Wq_s : Wq_t;
    const float* Wk = br ? Wk_s : Wk_t;
    const float* Wv = br ? Wv_s : Wv_t;
    const float* Wd = br ? Wd_s : Wd_t;

    // ---- stage Wq, Wk, Wv into LDS (bf16, B-operand swizzle) ----
    {
      const float* srcs[3] = {Wq, Wk, Wv};
      unsigned short* dsts[3] = {rep, rep + 4096, Wdsw};
#pragma unroll
      for (int g = 0; g < 3; ++g) {
        const float4v u = *reinterpret_cast<const float4v*>(srcs[g] + sd * 64 + se0);
        unsigned short* dst = dsts[g];
#pragma unroll
        for (int i = 0; i < 4; ++i) dst[sbase + (se0 + i) * 8] = f2bf(u[i]);
      }
    }
    __syncthreads();

    // ---- phase 1: Q,K,V = X @ W. K,V -> LDS; Q D-frags kept in registers ----
    short4v qd[2][4];  // Q D-frags, bf16-packed: qd[mi][nt][r] = Q[mt*16+quad*4+r][nt*16+ln]
#pragma unroll 1
    for (int mi = 0; mi < 2; ++mi) {
      const int mt = wv + mi * 16;  // m-tile 0..31
      const int mrow = mt * 16 + ln;
      short8 xa0, xa1;
      {
        const float4v* p0 = reinterpret_cast<const float4v*>(xb + mrow * 64 + quad * 8);
        const float4v u0 = p0[0], v0 = p0[1];
        const float4v* p1 = reinterpret_cast<const float4v*>(xb + mrow * 64 + 32 + quad * 8);
        const float4v u1 = p1[0], v1 = p1[1];
#pragma unroll
        for (int i = 0; i < 4; ++i) {
          xa0[i] = (short)f2bf(u0[i]);
          xa0[4 + i] = (short)f2bf(v0[i]);
          xa1[i] = (short)f2bf(u1[i]);
          xa1[4 + i] = (short)f2bf(v1[i]);
        }
      }
#pragma unroll
      for (int g = 0; g < 3; ++g) {
        const unsigned short* Wl = (g == 0) ? rep : (g == 1) ? (rep + 4096) : Wdsw;
#pragma unroll
        for (int nt = 0; nt < 4; ++nt) {
          const short8 b0 = *reinterpret_cast<const short8*>(Wl + quad * 512 + (nt * 16 + ln) * 8);
          const short8 b1 =
              *reinterpret_cast<const short8*>(Wl + (4 + quad) * 512 + (nt * 16 + ln) * 8);
          float4v acc = {0.f, 0.f, 0.f, 0.f};
          acc = MFMA16(xa0, b0, acc);
          acc = MFMA16(xa1, b1, acc);
          // D-frag: element (row = mt*16 + quad*4 + r, col e = nt*16 + ln)
          if (g == 0) {
            short4v pk;
#pragma unroll
            for (int r = 0; r < 4; ++r) pk[r] = (short)f2bf(acc[r]);
            qd[mi][nt] = pk;
          } else if (g == 1) {
            const int ehi = nt * 2 + (ln >> 3);
            const int elo = ln & 7;
#pragma unroll
            for (int r = 0; r < 4; ++r)
              Ksw[ehi * 4096 + (mt * 16 + quad * 4 + r) * 8 + elo] = f2bf(acc[r]);
          } else {
            short4v pk;
#pragma unroll
            for (int r = 0; r < 4; ++r) pk[r] = (short)f2bf(acc[r]);
            const int vbase = (mt * 2 + (quad >> 1)) * 512 + (nt * 16 + ln) * 8 + (quad & 1) * 4;
            *reinterpret_cast<short4v*>(Vsw + vbase) = pk;
          }
        }
      }
    }
    __syncthreads();

    // ---- stage Wd (overwrites Wv staging; V already built) ----
    {
      const float4v u = *reinterpret_cast<const float4v*>(Wd + sd * 64 + se0);
#pragma unroll
      for (int i = 0; i < 4; ++i) Wdsw[sbase + (se0 + i) * 8] = f2bf(u[i]);
    }
    __syncthreads();

    // ---- phase 2/3: per-wave Q-tiles ----
    unsigned short* buf = rep + wv * 640;  // 16 x 40 repack buffer (wave-local)
#pragma unroll 1
    for (int qi = 0; qi < 2; ++qi) {
      const int qt = wv + qi * 16;

      // Q D-frag -> A-frag repack via LDS (two 32-col passes)
      short8 q0, q1;
#pragma unroll
      for (int nt = 0; nt < 2; ++nt)
#pragma unroll
        for (int r = 0; r < 4; ++r)
          buf[(quad * 4 + r) * 40 + nt * 16 + ln] = (unsigned short)qd[qi][nt][r];
      asm volatile("s_waitcnt lgkmcnt(0)" ::: "memory");
      q0 = *reinterpret_cast<const short8*>(buf + ln * 40 + quad * 8);
#pragma unroll
      for (int nt = 2; nt < 4; ++nt)
#pragma unroll
        for (int r = 0; r < 4; ++r)
          buf[(quad * 4 + r) * 40 + (nt - 2) * 16 + ln] = (unsigned short)qd[qi][nt][r];
      asm volatile("s_waitcnt lgkmcnt(0)" ::: "memory");
      q1 = *reinterpret_cast<const short8*>(buf + ln * 40 + quad * 8);

      float sum[4] = {0.f, 0.f, 0.f, 0.f};
      float4v o[4];
#pragma unroll
      for (int i = 0; i < 4; ++i) o[i] = (float4v){0.f, 0.f, 0.f, 0.f};

      // chunks of 8 score tiles: 16 back-to-back QK MFMAs, then exp/pack/PV
#pragma unroll 1
      for (int sc = 0; sc < 4; ++sc) {
        float4v s[8];
#pragma unroll
        for (int t = 0; t < 8; ++t) {
          const int nt = sc * 8 + t;
          const short8 k0 =
              *reinterpret_cast<const short8*>(Ksw + quad * 4096 + (nt * 16 + ln) * 8);
          const short8 k1 =
              *reinterpret_cast<const short8*>(Ksw + (4 + quad) * 4096 + (nt * 16 + ln) * 8);
          float4v acc = {0.f, 0.f, 0.f, 0.f};
          acc = MFMA16(q0, k0, acc);
          acc = MFMA16(q1, k1, acc);
          s[t] = acc;
        }
#pragma unroll
        for (int kc2 = 0; kc2 < 4; ++kc2) {
          const int kcg = sc * 4 + kc2;
#pragma unroll
          for (int t2 = 0; t2 < 2; ++t2) {
            const float4v sv = s[kc2 * 2 + t2];
#pragma unroll
            for (int r = 0; r < 4; ++r) {
              const float p = __expf(sv[r] * 0.125f);  // no max-shift: |s|<~10, fp32-safe
              sum[r] += p;
              buf[(quad * 4 + r) * 40 + t2 * 16 + ln] = f2bf(p);
            }
          }
          asm volatile("s_waitcnt lgkmcnt(0)" ::: "memory");  // cross-lane RAW
          const short8 pa = *reinterpret_cast<const short8*>(buf + ln * 40 + quad * 8);
#pragma unroll
          for (int nto = 0; nto < 4; ++nto) {
            const short8 vf =
                *reinterpret_cast<const short8*>(Vsw + (kcg * 4 + quad) * 512 + (nto * 16 + ln) * 8);
            o[nto] = MFMA16(pa, vf, o[nto]);
          }
          // no WAR drain: DS pipe is in-order per wave
        }
      }

      // row sums -> 1/sum
#pragma unroll
      for (int dd = 1; dd < 16; dd <<= 1)
#pragma unroll
        for (int r = 0; r < 4; ++r) sum[r] += __shfl_xor(sum[r], dd, 64);
      float inv[4];
#pragma unroll
      for (int r = 0; r < 4; ++r) inv[r] = 1.0f / sum[r];

      // O (16x64) -> A-layout via buf, two 32-col passes
#pragma unroll
      for (int nto = 0; nto < 2; ++nto)
#pragma unroll
        for (int r = 0; r < 4; ++r)
          buf[(quad * 4 + r) * 40 + nto * 16 + ln] = f2bf(o[nto][r] * inv[r]);
      asm volatile("s_waitcnt lgkmcnt(0)" ::: "memory");
      const short8 a0 = *reinterpret_cast<const short8*>(buf + ln * 40 + quad * 8);
#pragma unroll
      for (int nto = 2; nto < 4; ++nto)
#pragma unroll
        for (int r = 0; r < 4; ++r)
          buf[(quad * 4 + r) * 40 + (nto - 2) * 16 + ln] = f2bf(o[nto][r] * inv[r]);
      asm volatile("s_waitcnt lgkmcnt(0)" ::: "memory");
      const short8 a1 = *reinterpret_cast<const short8*>(buf + ln * 40 + quad * 8);

      // dense: O @ Wd; br0 parks in d_out (L3-absorbed), br1 fused epilogue
#pragma unroll
      for (int nt = 0; nt < 4; ++nt) {
        const short8 w0 = *reinterpret_cast<const short8*>(Wdsw + quad * 512 + (nt * 16 + ln) * 8);
        const short8 w1 =
            *reinterpret_cast<const short8*>(Wdsw + (4 + quad) * 512 + (nt * 16 + ln) * 8);
        float4v d4 = {0.f, 0.f, 0.f, 0.f};
        d4 = MFMA16(a0, w0, d4);
        d4 = MFMA16(a1, w1, d4);
        const int m0 = qt * 16 + quad * 4;
        const int col = nt * 16 + ln;
        if (br == 0) {
#pragma unroll
          for (int r = 0; r < 4; ++r) outb[(m0 + r) * 64 + col] = d4[r];
        } else {
#pragma unroll
          for (int r = 0; r < 4; ++r) {
            const float z = outb[(m0 + r) * 64 + col] + d4[r] + bdsum[nt];
            const float gate = 1.0f / (1.0f + __expf(-z));
            outb[(m0 + r) * 64 + col] = xb[(m0 + r) * 64 + col] * gate;
          }
        }
      }
    }
    __syncthreads();  // protect LDS before next branch restages
  }
}

extern "C" void kernel_launch(void* const* d_in, const int* in_sizes, int n_in,
                              void* d_out, int out_size, void* d_ws, size_t ws_size,
                              hipStream_t stream) {
  const float* x = (const float*)d_in[0];
  const float* Wq_t = (const float*)d_in[1];
  const float* Wk_t = (const float*)d_in[2];
  const float* Wv_t = (const float*)d_in[3];
  const float* Wq_s = (const float*)d_in[4];
  const float* Wk_s = (const float*)d_in[5];
  const float* Wv_s = (const float*)d_in[6];
  const float* Wd_t = (const float*)d_in[7];
  const float* bd_t = (const float*)d_in[8];
  const float* Wd_s = (const float*)d_in[9];
  const float* bd_s = (const float*)d_in[10];
  float* out = (float*)d_out;

  hipFuncSetAttribute(reinterpret_cast<const void*>(ts_attn_fused),
                      hipFuncAttributeMaxDynamicSharedMemorySize, LDS_TOTAL_BYTES);
  ts_attn_fused<<<dim3(256), dim3(kThreads), LDS_TOTAL_BYTES, stream>>>(
      x, Wq_t, Wk_t, Wv_t, Wq_s, Wk_s, Wv_s, Wd_t, bd_t, Wd_s, bd_s, out);
}